// Round 12
// baseline (228.621 us; speedup 1.0000x reference)
//
#include <hip/hip_runtime.h>
#include <math.h>

#define BB 8
#define SS 2048
#define DD 512
#define HH 8
#define MM (BB*SS)   // 16384

// scan_h chunking
#define CHK 128   // chunks over t
#define CL  16    // stored steps per chunk (CHK*CL == SS)
#define CW  48    // warm-up steps (contraction ~e^-0.87/step; mean e^-42)

// retr fused-EMA chunking
#define RT 64     // stored steps per wave
#define RW 128    // EMA warm-up steps

typedef unsigned short u16;
typedef unsigned int   u32;
typedef float f32x4 __attribute__((ext_vector_type(4)));
typedef short s16x8 __attribute__((ext_vector_type(8)));

__device__ __forceinline__ u16 f2bf(float x){
  union { float f; unsigned u; } c; c.f = x;
  unsigned r = c.u + 0x7FFF + ((c.u >> 16) & 1);
  return (u16)(r >> 16);
}
__device__ __forceinline__ float bf2f(u16 x){
  union { unsigned u; float f; } c; c.u = ((unsigned)x) << 16;
  return c.f;
}
__device__ __forceinline__ void gload16(const u16* g, u16* l){
  __builtin_amdgcn_global_load_lds(
      (const __attribute__((address_space(1))) unsigned int*)g,
      (__attribute__((address_space(3))) unsigned int*)l, 16, 0, 0);
}

// ---------------- single fused prep kernel ----------------
__global__ void prep_all(const float* __restrict__ ipWr, const float* __restrict__ ipWi,
                         const float* __restrict__ Wqkv,
                         const float* __restrict__ opWr, const float* __restrict__ opWi,
                         const float* __restrict__ ipbr, const float* __restrict__ ipbi,
                         const float* __restrict__ la,
                         u16* __restrict__ W1, u16* __restrict__ Wq, u16* __restrict__ W3,
                         float* __restrict__ tphi2, float* __restrict__ bc,
                         float* __restrict__ alph){
  int id = blockIdx.x*256 + threadIdx.x;
  if (id < 524288){
    // W1[n][2d] = Wr+Wi (cos), W1[n][2d+1] = Wr-Wi (sin)
    int n = id >> 10, k = id & 1023;
    int d = k >> 1;
    float v = (k & 1) ? (ipWr[n*512+d] - ipWi[n*512+d])
                      : (ipWr[n*512+d] + ipWi[n*512+d]);
    W1[id] = f2bf(v);
  } else if (id < 1310720){
    int i = id - 524288;              // 1536*512, already [N][K]
    Wq[i] = f2bf(Wqkv[i]);
  } else if (id < 1835008){
    int i = id - 1310720;             // 1024*512
    int n = i >> 9, k = i & 511;
    W3[i] = f2bf((n < 512) ? opWr[n*512+k] : opWi[(n-512)*512+k]);
  } else if (id < 1837056){
    int t = id - 1835008;
    const float PHI_F    = 1.61803398874989484820f;
    const float TWO_PI_F = 6.28318530717958647693f;
    tphi2[t] = 2.0f * fmodf((float)t * PHI_F, TWO_PI_F);
  } else if (id < 1837568){
    int t = id - 1837056;
    bc[t] = ipbr[t] + ipbi[t];
  } else if (id < 1837576){
    int t = id - 1837568;
    alph[t] = 1.0f/(1.0f + expf(-la[t]));
  }
}

// ---------------- phase 1: h-recurrence, chunked restart ----------------
__global__ __launch_bounds__(256) void scan_h(const float* __restrict__ w,
                                              const float* __restrict__ bb,
                                              const float* __restrict__ tphi2,
                                              u32* __restrict__ X32){
  const int e = blockIdx.x*256 + threadIdx.x;   // 0..4095 = B*D
  const int c = blockIdx.y;                     // chunk
  const int b = e >> 9;
  const int d = e & 511;
  const float SQRT2 = 1.41421356237309504880f;
  const float PI_4  = 0.78539816339744830962f;
  const int tstart = c*CL;
  int t0 = tstart - CW; if (t0 < 0) t0 = 0;
  const int nw = tstart - t0;                   // 0,16,32,48 (multiple of 8)

  const float* wp = w  + ((size_t)b*SS + t0)*DD + d;
  const float* bp = bb + ((size_t)b*SS + t0)*DD + d;
  const float* tp = tphi2 + t0;

  const int U = 8;
  float wv[U], bv[U], wn[U], bn[U];

  float ss = 0.f;   // sin(theta + pi/4); hr+hi = sqrt2*ss
  const int ngw = nw >> 3;
  if (ngw > 0){
    #pragma unroll
    for (int i=0;i<U;i++){ wv[i] = wp[(size_t)i*DD]; bv[i] = bp[(size_t)i*DD]; }
    for (int gg=0; gg<ngw; ++gg){
      if (gg+1 < ngw){
        const float* wnp = wp + (size_t)(gg+1)*U*DD;
        const float* bnp = bp + (size_t)(gg+1)*U*DD;
        #pragma unroll
        for (int i=0;i<U;i++){ wn[i] = wnp[(size_t)i*DD]; bn[i] = bnp[(size_t)i*DD]; }
      }
      #pragma unroll
      for (int i=0;i<U;i++){
        float rwl2 = SQRT2 * __builtin_amdgcn_rcpf(1.0f + fabsf(wv[i]));
        float cw   = fmaf(2.0f, bv[i], tp[gg*U+i]) + PI_4;
        ss = __sinf(fmaf(ss, rwl2, cw));
      }
      #pragma unroll
      for (int i=0;i<U;i++){ wv[i]=wn[i]; bv[i]=bn[i]; }
    }
  }
  float hs = SQRT2 * ss;   // = hr + hi

  const float* wq = wp + (size_t)nw*DD;
  const float* bq = bp + (size_t)nw*DD;
  const float* tq = tp + nw;
  u32* xp = X32 + (size_t)(b*SS + tstart)*512 + d;

  #pragma unroll
  for (int i=0;i<U;i++){ wv[i] = wq[(size_t)i*DD]; bv[i] = bq[(size_t)i*DD]; }
  for (int gg=0; gg<CL/U; ++gg){
    if (gg+1 < CL/U){
      const float* wnp = wq + (size_t)(gg+1)*U*DD;
      const float* bnp = bq + (size_t)(gg+1)*U*DD;
      #pragma unroll
      for (int i=0;i<U;i++){ wn[i] = wnp[(size_t)i*DD]; bn[i] = bnp[(size_t)i*DD]; }
    }
    #pragma unroll
    for (int i=0;i<U;i++){
      float rwl = __builtin_amdgcn_rcpf(1.0f + fabsf(wv[i]));
      float cc  = fmaf(2.0f, bv[i], tq[gg*U+i]);
      float theta = fmaf(hs, rwl, cc);
      float sn = __sinf(theta);
      float cs = __cosf(theta);
      hs = cs + sn;
      xp[(size_t)(gg*U+i)*512] = (u32)f2bf(cs) | ((u32)f2bf(sn) << 16);
    }
    #pragma unroll
    for (int i=0;i<U;i++){ wv[i]=wn[i]; bv[i]=bn[i]; }
  }
}

// ---------------- bf16 MFMA GEMM: C[M x N] = A[M x K] @ W[N x K]^T ----------------
// Hybrid operand routing (round-12): A via LDS (4 rotating 8KB regions, 3-ahead
// gload_lds, counted vmcnt), B DIRECT from global/L2 into registers (prefetched
// one phase ahead, double-buffered static regs). Halves LDS-pipe traffic — the
// measured 5:1 LDS:MFMA imbalance that capped MfmaUtil at ~21% for 4 schedules.
// BM=128 x BN=256, 8 waves (2M x 4N, wave tile 64x64). Per phase:
//   4x ds_read_b128 (A-frags, region h&3) | 4x global B-frag loads (h+1)
//   | 1x gload_lds (A half h+3) -> barrier -> setprio(1) -> 16 MFMA ->
//   setprio(0) -> vmcnt(6|5|4) (A(h+1) landed; rest in flight) -> barrier.
// In-order vmcnt retirement => counts safe even with compiler-placed B loads
// (B(h+1) always issued after A(h+1); "memory" clobbers confine them per-phase).
// Bijective XCD swizzle. A LDS slot (row,kg) holds k-chunk kg^((row>>1)&3).
// EPI: 1 = f32 split C0/C1 stride 512; 2 = bf16->C2 stride N.
template<int TAG, int EPI>
__global__ __launch_bounds__(512) void gemm_bf16(const u16* __restrict__ A,
                                                 const u16* __restrict__ W,
                                                 float* __restrict__ C0,
                                                 float* __restrict__ C1,
                                                 u16* __restrict__ C2,
                                                 int N, int K){
  __shared__ __align__(16) u16 As[4][128*32];   // 8KB per region, 32KB total
  const int tid  = threadIdx.x;
  const int nwgx = gridDim.x;
  const int nwg  = nwgx * gridDim.y;
  const int lin  = blockIdx.y * nwgx + blockIdx.x;
  const int qq   = nwg >> 3;
  const int logi = (lin & 7) * qq + (lin >> 3);
  const int m0   = (logi / nwgx) * 128;
  const int n0   = (logi % nwgx) * 256;

  const int wave = tid >> 6;
  const int lane = tid & 63;
  const int wm   = wave >> 2;        // 0..1 (M half)
  const int wn   = wave & 3;         // 0..3 (N quarter)
  const int l15  = lane & 15;
  const int g    = lane >> 4;

  // A staging: 512 threads x 16B = 8KB = full 128x32 half-tile; thread t ->
  // row t>>2, LDS k-slot t&3, source k-chunk (t&3)^((t>>3)&3)  (involution).
  const int kgs = (tid & 3) ^ ((tid >> 3) & 3);
  const u16* Asrc = A + (size_t)(m0 + (tid>>2)) * K + kgs*8;
  const int dA = tid*8;
  // B fragment base: lane (g,l15), frag s covers W rows n0+wn*64+s*16+l15,
  // k-chunk g of the current 32-k half.
  const u16* Bf = W + (size_t)(n0 + wn*64 + l15) * K + g*8;

  f32x4 acc[4][4];
  #pragma unroll
  for (int i=0;i<4;i++)
    #pragma unroll
    for (int j=0;j<4;j++) acc[i][j] = (f32x4){0.f,0.f,0.f,0.f};

  const int H = K >> 5;              // 32-col halves (16 or 32, even)
  s16x8 b0[4], b1[4];

#define PHASE(hh, bcur, bnxt) do {                                        \
    const u16* Ah = &As[(hh)&3][0];                                       \
    s16x8 af[4];                                                          \
    _Pragma("unroll")                                                     \
    for (int s=0;s<4;s++){                                                \
      int rA = wm*64 + s*16 + l15;                                        \
      af[s] = *(const s16x8*)&Ah[rA*32 + ((g ^ ((rA>>1)&3))*8)];          \
    }                                                                     \
    if ((hh)+1 < H){                                                      \
      _Pragma("unroll")                                                   \
      for (int s=0;s<4;s++)                                               \
        bnxt[s] = *(const s16x8*)(Bf + (size_t)s*16*K + ((hh)+1)*32);     \
    }                                                                     \
    if ((hh)+3 < H)                                                       \
      gload16(Asrc + ((hh)+3)*32, &As[((hh)+3)&3][dA]);                   \
    __builtin_amdgcn_s_barrier();                                         \
    __builtin_amdgcn_s_setprio(1);                                        \
    _Pragma("unroll")                                                     \
    for (int mi=0;mi<4;mi++)                                              \
      _Pragma("unroll")                                                   \
      for (int ni=0;ni<4;ni++)                                            \
        acc[mi][ni] = __builtin_amdgcn_mfma_f32_16x16x32_bf16(af[mi], bcur[ni], acc[mi][ni], 0, 0, 0); \
    __builtin_amdgcn_s_setprio(0);                                        \
    {                                                                     \
      int rem = H - 1 - (hh);                                             \
      if      (rem >= 3) asm volatile("s_waitcnt vmcnt(6)" ::: "memory"); \
      else if (rem == 2) asm volatile("s_waitcnt vmcnt(5)" ::: "memory"); \
      else if (rem == 1) asm volatile("s_waitcnt vmcnt(4)" ::: "memory"); \
      if (rem > 0) __builtin_amdgcn_s_barrier();                          \
    }                                                                     \
  } while(0)

  // prologue: B(0) into b0; A halves 0..2 staged; wait A(0) (allows A1,A2 in flight)
  #pragma unroll
  for (int s=0;s<4;s++) b0[s] = *(const s16x8*)(Bf + (size_t)s*16*K);
  gload16(Asrc,      &As[0][dA]);
  gload16(Asrc + 32, &As[1][dA]);
  gload16(Asrc + 64, &As[2][dA]);
  asm volatile("s_waitcnt vmcnt(2)" ::: "memory");
  __builtin_amdgcn_s_barrier();

  for (int h = 0; h < H; h += 2){
    PHASE(h,   b0, b1);
    PHASE(h+1, b1, b0);
  }

#undef PHASE

  #pragma unroll
  for (int mi=0;mi<4;mi++){
    #pragma unroll
    for (int j=0;j<4;j++){
      int r = m0 + wm*64 + mi*16 + g*4 + j;
      #pragma unroll
      for (int ni=0;ni<4;ni++){
        int col = n0 + wn*64 + ni*16 + l15;
        float v = acc[mi][ni][j];
        if (EPI == 1){
          if (col < 512) C0[(size_t)r*512 + col]       = v;
          else           C1[(size_t)r*512 + (col-512)] = v;
        } else {
          C2[(size_t)r*N + col] = f2bf(v);
        }
      }
    }
  }
}

// ---------------- LayerNorm: xc = LN(y + bc)*g + b  (bf16 in, bf16 out) ----------------
__global__ __launch_bounds__(256) void ln_kernel(const u16* __restrict__ y,
                                                 const float* __restrict__ bc,
                                                 const float* __restrict__ g,
                                                 const float* __restrict__ bb,
                                                 u16* __restrict__ xc){
  const int row  = blockIdx.x*4 + (threadIdx.x >> 6);
  const int lane = threadIdx.x & 63;
  s16x8 v = *(const s16x8*)(y + (size_t)row*512 + lane*8);
  float4 c0 = ((const float4*)bc)[lane*2];
  float4 c1 = ((const float4*)bc)[lane*2+1];
  float f[8];
  f[0] = bf2f((u16)v[0]) + c0.x; f[1] = bf2f((u16)v[1]) + c0.y;
  f[2] = bf2f((u16)v[2]) + c0.z; f[3] = bf2f((u16)v[3]) + c0.w;
  f[4] = bf2f((u16)v[4]) + c1.x; f[5] = bf2f((u16)v[5]) + c1.y;
  f[6] = bf2f((u16)v[6]) + c1.z; f[7] = bf2f((u16)v[7]) + c1.w;
  float s = 0.f, s2 = 0.f;
  #pragma unroll
  for (int i=0;i<8;i++){ s += f[i]; s2 = fmaf(f[i], f[i], s2); }
  #pragma unroll
  for (int off=32; off>0; off>>=1){ s += __shfl_xor(s, off); s2 += __shfl_xor(s2, off); }
  float mean = s * (1.0f/512.0f);
  float var  = s2 * (1.0f/512.0f) - mean*mean;
  float rstd = rsqrtf(var + 1e-5f);
  float4 g0 = ((const float4*)g)[lane*2],  g1 = ((const float4*)g)[lane*2+1];
  float4 b0 = ((const float4*)bb)[lane*2], b1 = ((const float4*)bb)[lane*2+1];
  s16x8 o;
  o[0] = (short)f2bf((f[0]-mean)*rstd*g0.x + b0.x);
  o[1] = (short)f2bf((f[1]-mean)*rstd*g0.y + b0.y);
  o[2] = (short)f2bf((f[2]-mean)*rstd*g0.z + b0.z);
  o[3] = (short)f2bf((f[3]-mean)*rstd*g0.w + b0.w);
  o[4] = (short)f2bf((f[4]-mean)*rstd*g1.x + b1.x);
  o[5] = (short)f2bf((f[5]-mean)*rstd*g1.y + b1.y);
  o[6] = (short)f2bf((f[6]-mean)*rstd*g1.z + b1.z);
  o[7] = (short)f2bf((f[7]-mean)*rstd*g1.w + b1.w);
  *(s16x8*)(xc + (size_t)row*512 + lane*8) = o;
}

// ---------------- fused EMA + gate + retr ----------------
__global__ __launch_bounds__(256) void retr_fused(const u16* __restrict__ qkv,
                                                  const float* __restrict__ alph,
                                                  u16* __restrict__ retr){
  const int wid  = blockIdx.x*4 + (threadIdx.x >> 6);   // 0..2047
  const int lane = threadIdx.x & 63;
  const int c = wid & 31;                               // 32 chunks of RT=64
  const int h = (wid >> 5) & 7;
  const int b = wid >> 8;
  const float a  = alph[h];
  const float om = 1.0f - a;
  const int d  = h*64 + lane;
  const int t0 = c*RT;
  int w0 = t0 - RW; if (w0 < 0) w0 = 0;
  const int nw = t0 - w0;                      // multiple of 32

  const u16* vp = qkv + ((size_t)(b*SS + w0))*1536 + 1024 + d;
  float vs = 0.f;
  {
    const int U = 8;
    float vv[U], vn[U];
    const int ng = nw >> 3;
    if (ng > 0){
      #pragma unroll
      for (int i=0;i<U;i++) vv[i] = bf2f(vp[(size_t)i*1536]);
      for (int gg=0; gg<ng; ++gg){
        if (gg+1 < ng){
          const u16* vnp = vp + (size_t)(gg+1)*U*1536;
          #pragma unroll
          for (int i=0;i<U;i++) vn[i] = bf2f(vnp[(size_t)i*1536]);
        }
        #pragma unroll
        for (int i=0;i<U;i++) vs = fmaf(a, vv[i], om*vs);
        #pragma unroll
        for (int i=0;i<U;i++) vv[i] = vn[i];
      }
    }
  }
  const u16* qp = qkv + ((size_t)(b*SS + t0))*1536 + d;
  u16* op = retr + ((size_t)(b*SS + t0))*512 + d;
  #pragma unroll 4
  for (int i=0;i<RT;i++){
    float q  = bf2f(qp[(size_t)i*1536]);
    float kk = bf2f(qp[(size_t)i*1536 + 512]);
    float v  = bf2f(qp[(size_t)i*1536 + 1024]);
    vs = fmaf(a, v, om*vs);
    float p = q*kk;
    #pragma unroll
    for (int off=32; off>0; off>>=1) p += __shfl_xor(p, off);
    float gate = 1.0f/(1.0f + __expf(-p*0.125f));
    op[(size_t)i*512] = f2bf(gate * vs);
  }
}

extern "C" void kernel_launch(void* const* d_in, const int* in_sizes, int n_in,
                              void* d_out, int out_size, void* d_ws, size_t ws_size,
                              hipStream_t stream) {
  const float* w    = (const float*)d_in[0];
  const float* b    = (const float*)d_in[1];
  const float* ipWr = (const float*)d_in[2];
  const float* ipWi = (const float*)d_in[3];
  const float* ipbr = (const float*)d_in[4];
  const float* ipbi = (const float*)d_in[5];
  const float* lng  = (const float*)d_in[6];
  const float* lnb  = (const float*)d_in[7];
  const float* Wqkv = (const float*)d_in[8];
  const float* la   = (const float*)d_in[9];
  const float* opWr = (const float*)d_in[10];
  const float* opWi = (const float*)d_in[11];
  float* out0 = (float*)d_out;                    // (B,S,D) real part
  float* out1 = out0 + (size_t)MM*DD;             // imag part

  char* base = (char*)d_ws;
  u16*   W1    = (u16*)  (base + 0);              // 512x1024 bf16 (k-interleaved)
  u16*   Wq    = (u16*)  (base + 1048576);        // 1536x512 bf16
  u16*   W3    = (u16*)  (base + 2621440);        // 1024x512 bf16
  float* bc    = (float*)(base + 3670016);        // 512 f32
  float* alph  = (float*)(base + 3672064);        // 8 f32
  float* tphi2 = (float*)(base + 3672128);        // 2048 f32
  u32*   X32   = (u32*)  (base + 3680384);        // M*512 u32 (packed bf16 pair)
  u16*   y     = (u16*)  (base + 37234816);       // M*512 bf16
  u16*   xc    = (u16*)  (base + 54012032);       // M*512 bf16
  u16*   qkv   = (u16*)  (base + 70789248);       // M*1536 bf16
  u16*   retr  = (u16*)X32;                       // alias: X dead after GEMM1

  prep_all<<<7179,256,0,stream>>>(ipWr, ipWi, Wqkv, opWr, opWi, ipbr, ipbi, la,
                                  W1, Wq, W3, tphi2, bc, alph);

  scan_h<<<dim3(16,CHK),256,0,stream>>>(w, b, tphi2, X32);

  gemm_bf16<1,2><<<dim3(2,128),512,0,stream>>>((const u16*)X32, W1, nullptr, nullptr, y, 512, 1024);
  ln_kernel<<<4096,256,0,stream>>>(y, bc, lng, lnb, xc);
  gemm_bf16<2,2><<<dim3(6,128),512,0,stream>>>(xc, Wq, nullptr, nullptr, qkv, 1536, 512);

  retr_fused<<<512,256,0,stream>>>(qkv, alph, retr);

  gemm_bf16<3,1><<<dim3(4,128),512,0,stream>>>(retr, W3, out0, out1, nullptr, 1024, 512);
}

// Round 13
// 166.362 us; speedup vs baseline: 1.3742x; 1.3742x over previous
//
#include <hip/hip_runtime.h>
#include <math.h>

#define BB 8
#define SS 2048
#define DD 512
#define HH 8
#define MM (BB*SS)   // 16384

// scan_h chunking
#define CHK 128   // chunks over t
#define CL  16    // stored steps per chunk (CHK*CL == SS)
#define CW  48    // warm-up steps (contraction ~e^-0.87/step; mean e^-42)

// retr fused-EMA chunking
#define RT 64     // stored steps per wave
#define RW 128    // EMA warm-up steps

typedef unsigned short u16;
typedef unsigned int   u32;
typedef float f32x4 __attribute__((ext_vector_type(4)));
typedef short s16x8 __attribute__((ext_vector_type(8)));

__device__ __forceinline__ u16 f2bf(float x){
  union { float f; unsigned u; } c; c.f = x;
  unsigned r = c.u + 0x7FFF + ((c.u >> 16) & 1);
  return (u16)(r >> 16);
}
__device__ __forceinline__ float bf2f(u16 x){
  union { unsigned u; float f; } c; c.u = ((unsigned)x) << 16;
  return c.f;
}
__device__ __forceinline__ void gload16(const u16* g, u16* l){
  __builtin_amdgcn_global_load_lds(
      (const __attribute__((address_space(1))) unsigned int*)g,
      (__attribute__((address_space(3))) unsigned int*)l, 16, 0, 0);
}

// ---------------- single fused prep kernel ----------------
__global__ void prep_all(const float* __restrict__ ipWr, const float* __restrict__ ipWi,
                         const float* __restrict__ Wqkv,
                         const float* __restrict__ opWr, const float* __restrict__ opWi,
                         const float* __restrict__ ipbr, const float* __restrict__ ipbi,
                         const float* __restrict__ la,
                         u16* __restrict__ W1, u16* __restrict__ Wq, u16* __restrict__ W3,
                         float* __restrict__ tphi2, float* __restrict__ bc,
                         float* __restrict__ alph){
  int id = blockIdx.x*256 + threadIdx.x;
  if (id < 524288){
    // W1[n][2d] = Wr+Wi (cos), W1[n][2d+1] = Wr-Wi (sin)
    int n = id >> 10, k = id & 1023;
    int d = k >> 1;
    float v = (k & 1) ? (ipWr[n*512+d] - ipWi[n*512+d])
                      : (ipWr[n*512+d] + ipWi[n*512+d]);
    W1[id] = f2bf(v);
  } else if (id < 1310720){
    int i = id - 524288;              // 1536*512, already [N][K]
    Wq[i] = f2bf(Wqkv[i]);
  } else if (id < 1835008){
    int i = id - 1310720;             // 1024*512
    int n = i >> 9, k = i & 511;
    W3[i] = f2bf((n < 512) ? opWr[n*512+k] : opWi[(n-512)*512+k]);
  } else if (id < 1837056){
    int t = id - 1835008;
    const float PHI_F    = 1.61803398874989484820f;
    const float TWO_PI_F = 6.28318530717958647693f;
    tphi2[t] = 2.0f * fmodf((float)t * PHI_F, TWO_PI_F);
  } else if (id < 1837568){
    int t = id - 1837056;
    bc[t] = ipbr[t] + ipbi[t];
  } else if (id < 1837576){
    int t = id - 1837568;
    alph[t] = 1.0f/(1.0f + expf(-la[t]));
  }
}

// ---------------- phase 1: h-recurrence, chunked restart ----------------
__global__ __launch_bounds__(256) void scan_h(const float* __restrict__ w,
                                              const float* __restrict__ bb,
                                              const float* __restrict__ tphi2,
                                              u32* __restrict__ X32){
  const int e = blockIdx.x*256 + threadIdx.x;   // 0..4095 = B*D
  const int c = blockIdx.y;                     // chunk
  const int b = e >> 9;
  const int d = e & 511;
  const float SQRT2 = 1.41421356237309504880f;
  const float PI_4  = 0.78539816339744830962f;
  const int tstart = c*CL;
  int t0 = tstart - CW; if (t0 < 0) t0 = 0;
  const int nw = tstart - t0;                   // 0,16,32,48 (multiple of 8)

  const float* wp = w  + ((size_t)b*SS + t0)*DD + d;
  const float* bp = bb + ((size_t)b*SS + t0)*DD + d;
  const float* tp = tphi2 + t0;

  const int U = 8;
  float wv[U], bv[U], wn[U], bn[U];

  float ss = 0.f;   // sin(theta + pi/4); hr+hi = sqrt2*ss
  const int ngw = nw >> 3;
  if (ngw > 0){
    #pragma unroll
    for (int i=0;i<U;i++){ wv[i] = wp[(size_t)i*DD]; bv[i] = bp[(size_t)i*DD]; }
    for (int gg=0; gg<ngw; ++gg){
      if (gg+1 < ngw){
        const float* wnp = wp + (size_t)(gg+1)*U*DD;
        const float* bnp = bp + (size_t)(gg+1)*U*DD;
        #pragma unroll
        for (int i=0;i<U;i++){ wn[i] = wnp[(size_t)i*DD]; bn[i] = bnp[(size_t)i*DD]; }
      }
      #pragma unroll
      for (int i=0;i<U;i++){
        float rwl2 = SQRT2 * __builtin_amdgcn_rcpf(1.0f + fabsf(wv[i]));
        float cw   = fmaf(2.0f, bv[i], tp[gg*U+i]) + PI_4;
        ss = __sinf(fmaf(ss, rwl2, cw));
      }
      #pragma unroll
      for (int i=0;i<U;i++){ wv[i]=wn[i]; bv[i]=bn[i]; }
    }
  }
  float hs = SQRT2 * ss;   // = hr + hi

  const float* wq = wp + (size_t)nw*DD;
  const float* bq = bp + (size_t)nw*DD;
  const float* tq = tp + nw;
  u32* xp = X32 + (size_t)(b*SS + tstart)*512 + d;

  #pragma unroll
  for (int i=0;i<U;i++){ wv[i] = wq[(size_t)i*DD]; bv[i] = bq[(size_t)i*DD]; }
  for (int gg=0; gg<CL/U; ++gg){
    if (gg+1 < CL/U){
      const float* wnp = wq + (size_t)(gg+1)*U*DD;
      const float* bnp = bq + (size_t)(gg+1)*U*DD;
      #pragma unroll
      for (int i=0;i<U;i++){ wn[i] = wnp[(size_t)i*DD]; bn[i] = bnp[(size_t)i*DD]; }
    }
    #pragma unroll
    for (int i=0;i<U;i++){
      float rwl = __builtin_amdgcn_rcpf(1.0f + fabsf(wv[i]));
      float cc  = fmaf(2.0f, bv[i], tq[gg*U+i]);
      float theta = fmaf(hs, rwl, cc);
      float sn = __sinf(theta);
      float cs = __cosf(theta);
      hs = cs + sn;
      xp[(size_t)(gg*U+i)*512] = (u32)f2bf(cs) | ((u32)f2bf(sn) << 16);
    }
    #pragma unroll
    for (int i=0;i<U;i++){ wv[i]=wn[i]; bv[i]=bn[i]; }
  }
}

// ---------------- bf16 MFMA GEMM: C[M x N] = A[M x K] @ W[N x K]^T ----------------
// ROUND-8 STRUCTURE (empirical best of 5 schedules): 128x128 tile, BK=32,
// 4 waves. 3-deep counted-vmcnt pipeline: stage tile t+2, s_waitcnt vmcnt(8)
// (tile t landed, t+1/t+2 stay in flight), raw s_barrier, compute, barrier.
// 48KB LDS -> 3 blocks/CU. Bijective XCD swizzle. LDS slot (row,kg) holds
// k-chunk kg^((row>>1)&3); read applies same XOR (0 bank conflicts measured).
// EPI: 1 = f32 split C0/C1 stride 512; 2 = bf16->C2 stride N;
//      3 = bf16->C2 stride N with f32 bias[col] added before rounding.
template<int TAG, int EPI>
__global__ __launch_bounds__(256) void gemm_bf16(const u16* __restrict__ A,
                                                 const u16* __restrict__ W,
                                                 float* __restrict__ C0,
                                                 float* __restrict__ C1,
                                                 u16* __restrict__ C2,
                                                 const float* __restrict__ bias,
                                                 int N, int K){
  __shared__ __align__(16) u16 As[3][128*32];
  __shared__ __align__(16) u16 Bs[3][128*32];
  const int tid  = threadIdx.x;
  const int nwgx = gridDim.x;
  const int nwg  = nwgx * gridDim.y;
  const int lin  = blockIdx.y * nwgx + blockIdx.x;
  const int qq   = nwg >> 3;
  const int logi = (lin & 7) * qq + (lin >> 3);
  const int m0   = (logi / nwgx) * 128;
  const int n0   = (logi % nwgx) * 128;

  const int wave = tid >> 6;
  const int lane = tid & 63;
  const int wr   = wave >> 1, wc = wave & 1;
  const int l15  = lane & 15;
  const int g    = lane >> 4;

  const int rI   = lane >> 2;
  const int kgs  = (lane & 3) ^ ((lane >> 3) & 3);
  const int row0 = (wave*2+0)*16 + rI;
  const int row1 = (wave*2+1)*16 + rI;
  const u16* Asrc0 = A + (size_t)(m0 + row0) * K + kgs*8;
  const u16* Asrc1 = A + (size_t)(m0 + row1) * K + kgs*8;
  const u16* Bsrc0 = W + (size_t)(n0 + row0) * K + kgs*8;
  const u16* Bsrc1 = W + (size_t)(n0 + row1) * K + kgs*8;
  const int ld0 = (wave*2+0)*512;
  const int ld1 = (wave*2+1)*512;

  f32x4 acc[4][4];
  #pragma unroll
  for (int i=0;i<4;i++)
    #pragma unroll
    for (int j=0;j<4;j++) acc[i][j] = (f32x4){0.f,0.f,0.f,0.f};

#define STAGE(buf, koff) do {                      \
    gload16(Asrc0 + (koff), &As[buf][ld0]);        \
    gload16(Asrc1 + (koff), &As[buf][ld1]);        \
    gload16(Bsrc0 + (koff), &Bs[buf][ld0]);        \
    gload16(Bsrc1 + (koff), &Bs[buf][ld1]);        \
  } while(0)

#define COMPUTE(buf) do {                                            \
    s16x8 af[4], bf[4];                                              \
    _Pragma("unroll")                                                \
    for (int s=0;s<4;s++){                                           \
      int rA = wr*64 + s*16 + l15;                                   \
      af[s] = *(const s16x8*)&As[buf][rA*32 + ((g ^ ((rA>>1)&3))*8)];\
      int rB = wc*64 + s*16 + l15;                                   \
      bf[s] = *(const s16x8*)&Bs[buf][rB*32 + ((g ^ ((rB>>1)&3))*8)];\
    }                                                                \
    _Pragma("unroll")                                                \
    for (int mi=0;mi<4;mi++)                                         \
      _Pragma("unroll")                                              \
      for (int ni=0;ni<4;ni++)                                       \
        acc[mi][ni] = __builtin_amdgcn_mfma_f32_16x16x32_bf16(af[mi], bf[ni], acc[mi][ni], 0, 0, 0); \
  } while(0)

  const int nt = K >> 5;          // K/32 tiles (>=16 for all our shapes)
  STAGE(0, 0);
  STAGE(1, 32);
  int cur = 0;                    // buffer holding tile t
  for (int t = 0; t < nt; ++t){
    if (t+2 < nt){
      int nb = cur+2; if (nb >= 3) nb -= 3;
      STAGE(nb, (t+2)*32);
      asm volatile("s_waitcnt vmcnt(8)" ::: "memory");   // tile t landed
    } else if (t+1 < nt){
      asm volatile("s_waitcnt vmcnt(4)" ::: "memory");
    } else {
      asm volatile("s_waitcnt vmcnt(0)" ::: "memory");
    }
    __builtin_amdgcn_s_barrier();      // all waves' tile-t DMAs landed
    COMPUTE(cur);
    asm volatile("" ::: "memory");
    __builtin_amdgcn_s_barrier();      // all waves done reading buf before re-stage
    cur = (cur==2) ? 0 : cur+1;
  }

#undef STAGE
#undef COMPUTE

  #pragma unroll
  for (int mi=0;mi<4;mi++){
    #pragma unroll
    for (int j=0;j<4;j++){
      int r = m0 + wr*64 + mi*16 + g*4 + j;
      #pragma unroll
      for (int ni=0;ni<4;ni++){
        int col = n0 + wc*64 + ni*16 + l15;
        float v = acc[mi][ni][j];
        if (EPI == 1){
          if (col < 512) C0[(size_t)r*512 + col]       = v;
          else           C1[(size_t)r*512 + (col-512)] = v;
        } else if (EPI == 2){
          C2[(size_t)r*N + col] = f2bf(v);
        } else {
          C2[(size_t)r*N + col] = f2bf(v + bias[col]);
        }
      }
    }
  }
}

// ---------------- LayerNorm: xc = LN(y)*g + b  (bf16 in — bias pre-added in gemm1) ----------------
__global__ __launch_bounds__(256) void ln_kernel(const u16* __restrict__ y,
                                                 const float* __restrict__ g,
                                                 const float* __restrict__ bb,
                                                 u16* __restrict__ xc){
  const int row  = blockIdx.x*4 + (threadIdx.x >> 6);
  const int lane = threadIdx.x & 63;
  s16x8 v = *(const s16x8*)(y + (size_t)row*512 + lane*8);
  float f[8];
  #pragma unroll
  for (int i=0;i<8;i++) f[i] = bf2f((u16)v[i]);
  float s = 0.f, s2 = 0.f;
  #pragma unroll
  for (int i=0;i<8;i++){ s += f[i]; s2 = fmaf(f[i], f[i], s2); }
  #pragma unroll
  for (int off=32; off>0; off>>=1){ s += __shfl_xor(s, off); s2 += __shfl_xor(s2, off); }
  float mean = s * (1.0f/512.0f);
  float var  = s2 * (1.0f/512.0f) - mean*mean;
  float rstd = rsqrtf(var + 1e-5f);
  float4 g0 = ((const float4*)g)[lane*2],  g1 = ((const float4*)g)[lane*2+1];
  float4 b0 = ((const float4*)bb)[lane*2], b1 = ((const float4*)bb)[lane*2+1];
  s16x8 o;
  o[0] = (short)f2bf((f[0]-mean)*rstd*g0.x + b0.x);
  o[1] = (short)f2bf((f[1]-mean)*rstd*g0.y + b0.y);
  o[2] = (short)f2bf((f[2]-mean)*rstd*g0.z + b0.z);
  o[3] = (short)f2bf((f[3]-mean)*rstd*g0.w + b0.w);
  o[4] = (short)f2bf((f[4]-mean)*rstd*g1.x + b1.x);
  o[5] = (short)f2bf((f[5]-mean)*rstd*g1.y + b1.y);
  o[6] = (short)f2bf((f[6]-mean)*rstd*g1.z + b1.z);
  o[7] = (short)f2bf((f[7]-mean)*rstd*g1.w + b1.w);
  *(s16x8*)(xc + (size_t)row*512 + lane*8) = o;
}

// ---------------- fused EMA + gate + retr ----------------
__global__ __launch_bounds__(256) void retr_fused(const u16* __restrict__ qkv,
                                                  const float* __restrict__ alph,
                                                  u16* __restrict__ retr){
  const int wid  = blockIdx.x*4 + (threadIdx.x >> 6);   // 0..2047
  const int lane = threadIdx.x & 63;
  const int c = wid & 31;                               // 32 chunks of RT=64
  const int h = (wid >> 5) & 7;
  const int b = wid >> 8;
  const float a  = alph[h];
  const float om = 1.0f - a;
  const int d  = h*64 + lane;
  const int t0 = c*RT;
  int w0 = t0 - RW; if (w0 < 0) w0 = 0;
  const int nw = t0 - w0;                      // multiple of 32

  const u16* vp = qkv + ((size_t)(b*SS + w0))*1536 + 1024 + d;
  float vs = 0.f;
  {
    const int U = 8;
    float vv[U], vn[U];
    const int ng = nw >> 3;
    if (ng > 0){
      #pragma unroll
      for (int i=0;i<U;i++) vv[i] = bf2f(vp[(size_t)i*1536]);
      for (int gg=0; gg<ng; ++gg){
        if (gg+1 < ng){
          const u16* vnp = vp + (size_t)(gg+1)*U*1536;
          #pragma unroll
          for (int i=0;i<U;i++) vn[i] = bf2f(vnp[(size_t)i*1536]);
        }
        #pragma unroll
        for (int i=0;i<U;i++) vs = fmaf(a, vv[i], om*vs);
        #pragma unroll
        for (int i=0;i<U;i++) vv[i] = vn[i];
      }
    }
  }
  const u16* qp = qkv + ((size_t)(b*SS + t0))*1536 + d;
  u16* op = retr + ((size_t)(b*SS + t0))*512 + d;
  #pragma unroll 4
  for (int i=0;i<RT;i++){
    float q  = bf2f(qp[(size_t)i*1536]);
    float kk = bf2f(qp[(size_t)i*1536 + 512]);
    float v  = bf2f(qp[(size_t)i*1536 + 1024]);
    vs = fmaf(a, v, om*vs);
    float p = q*kk;
    #pragma unroll
    for (int off=32; off>0; off>>=1) p += __shfl_xor(p, off);
    float gate = 1.0f/(1.0f + __expf(-p*0.125f));
    op[(size_t)i*512] = f2bf(gate * vs);
  }
}

extern "C" void kernel_launch(void* const* d_in, const int* in_sizes, int n_in,
                              void* d_out, int out_size, void* d_ws, size_t ws_size,
                              hipStream_t stream) {
  const float* w    = (const float*)d_in[0];
  const float* b    = (const float*)d_in[1];
  const float* ipWr = (const float*)d_in[2];
  const float* ipWi = (const float*)d_in[3];
  const float* ipbr = (const float*)d_in[4];
  const float* ipbi = (const float*)d_in[5];
  const float* lng  = (const float*)d_in[6];
  const float* lnb  = (const float*)d_in[7];
  const float* Wqkv = (const float*)d_in[8];
  const float* la   = (const float*)d_in[9];
  const float* opWr = (const float*)d_in[10];
  const float* opWi = (const float*)d_in[11];
  float* out0 = (float*)d_out;                    // (B,S,D) real part
  float* out1 = out0 + (size_t)MM*DD;             // imag part

  char* base = (char*)d_ws;
  u16*   W1    = (u16*)  (base + 0);              // 512x1024 bf16 (k-interleaved)
  u16*   Wq    = (u16*)  (base + 1048576);        // 1536x512 bf16
  u16*   W3    = (u16*)  (base + 2621440);        // 1024x512 bf16
  float* bc    = (float*)(base + 3670016);        // 512 f32
  float* alph  = (float*)(base + 3672064);        // 8 f32
  float* tphi2 = (float*)(base + 3672128);        // 2048 f32
  u32*   X32   = (u32*)  (base + 3680384);        // M*512 u32 (packed bf16 pair)
  u16*   y     = (u16*)  (base + 37234816);       // M*512 bf16
  u16*   xc    = (u16*)  (base + 54012032);       // M*512 bf16
  u16*   qkv   = (u16*)  (base + 70789248);       // M*1536 bf16
  u16*   retr  = (u16*)X32;                       // alias: X dead after GEMM1

  prep_all<<<7179,256,0,stream>>>(ipWr, ipWi, Wqkv, opWr, opWi, ipbr, ipbi, la,
                                  W1, Wq, W3, tphi2, bc, alph);

  scan_h<<<dim3(16,CHK),256,0,stream>>>(w, b, tphi2, X32);

  gemm_bf16<1,3><<<dim3(4,128),256,0,stream>>>((const u16*)X32, W1, nullptr, nullptr, y, bc, 512, 1024);
  ln_kernel<<<4096,256,0,stream>>>(y, lng, lnb, xc);
  gemm_bf16<2,2><<<dim3(12,128),256,0,stream>>>(xc, Wq, nullptr, nullptr, qkv, nullptr, 1536, 512);

  retr_fused<<<512,256,0,stream>>>(qkv, alph, retr);

  gemm_bf16<3,1><<<dim3(8,128),256,0,stream>>>(retr, W3, out0, out1, nullptr, nullptr, 1024, 512);
}

// Round 14
// 155.535 us; speedup vs baseline: 1.4699x; 1.0696x over previous
//
#include <hip/hip_runtime.h>
#include <math.h>

#define BB 8
#define SS 2048
#define DD 512
#define HH 8
#define MM (BB*SS)   // 16384

// scan_h chunking
#define CHK 128   // chunks over t
#define CL  16    // stored steps per chunk (CHK*CL == SS)
#define CW  32    // warm-up steps (contraction ~e^-0.87/step; mean e^-28)

// retr fused-EMA chunking
#define RT 64     // stored steps per wave
#define RW 128    // EMA warm-up steps

typedef unsigned short u16;
typedef unsigned int   u32;
typedef float f32x4 __attribute__((ext_vector_type(4)));
typedef short s16x8 __attribute__((ext_vector_type(8)));

__device__ __forceinline__ u16 f2bf(float x){
  union { float f; unsigned u; } c; c.f = x;
  unsigned r = c.u + 0x7FFF + ((c.u >> 16) & 1);
  return (u16)(r >> 16);
}
__device__ __forceinline__ float bf2f(u16 x){
  union { unsigned u; float f; } c; c.u = ((unsigned)x) << 16;
  return c.f;
}
__device__ __forceinline__ void gload16(const u16* g, u16* l){
  __builtin_amdgcn_global_load_lds(
      (const __attribute__((address_space(1))) unsigned int*)g,
      (__attribute__((address_space(3))) unsigned int*)l, 16, 0, 0);
}

// ---------------- single fused prep kernel ----------------
// Weights stored FRAGMENT-MAJOR: for nb2 = n-64-block, ks = 32-k-step, s = frag:
//   Wfrag[((nb2*nK + ks)*4 + s)*512 + lane*8 + e] = W[n][k],
//   n = (nb2>>1)*128 + (nb2&1)*64 + s*16 + (lane&15),  k = ks*32 + (lane>>4)*8 + e.
// A wave's B-fragment load is then one contiguous 1KB global_load_dwordx4.
__global__ void prep_all(const float* __restrict__ ipWr, const float* __restrict__ ipWi,
                         const float* __restrict__ Wqkv,
                         const float* __restrict__ opWr, const float* __restrict__ opWi,
                         const float* __restrict__ ipbr, const float* __restrict__ ipbi,
                         const float* __restrict__ la,
                         u16* __restrict__ W1, u16* __restrict__ Wq, u16* __restrict__ W3,
                         float* __restrict__ tphi2, float* __restrict__ bc,
                         float* __restrict__ alph){
  int id = blockIdx.x*256 + threadIdx.x;
  if (id < 524288){
    // W1: N=512, K=1024 (k-interleaved cos/sin), nK=32
    int e = id & 7, lane = (id>>3) & 63, s = (id>>9) & 3;
    int rest = id >> 11, ks = rest & 31, nb2 = rest >> 5;
    int n = (nb2>>1)*128 + (nb2&1)*64 + s*16 + (lane&15);
    int k = ks*32 + (lane>>4)*8 + e;
    int d = k >> 1;
    float v = (k & 1) ? (ipWr[n*512+d] - ipWi[n*512+d])
                      : (ipWr[n*512+d] + ipWi[n*512+d]);
    W1[id] = f2bf(v);
  } else if (id < 1310720){
    // Wq: N=1536, K=512, nK=16
    int i = id - 524288;
    int e = i & 7, lane = (i>>3) & 63, s = (i>>9) & 3;
    int rest = i >> 11, ks = rest & 15, nb2 = rest >> 4;
    int n = (nb2>>1)*128 + (nb2&1)*64 + s*16 + (lane&15);
    int k = ks*32 + (lane>>4)*8 + e;
    Wq[i] = f2bf(Wqkv[n*512+k]);
  } else if (id < 1835008){
    // W3: N=1024, K=512, nK=16
    int i = id - 1310720;
    int e = i & 7, lane = (i>>3) & 63, s = (i>>9) & 3;
    int rest = i >> 11, ks = rest & 15, nb2 = rest >> 4;
    int n = (nb2>>1)*128 + (nb2&1)*64 + s*16 + (lane&15);
    int k = ks*32 + (lane>>4)*8 + e;
    W3[i] = f2bf((n < 512) ? opWr[n*512+k] : opWi[(n-512)*512+k]);
  } else if (id < 1837056){
    int t = id - 1835008;
    const float PHI_F    = 1.61803398874989484820f;
    const float TWO_PI_F = 6.28318530717958647693f;
    tphi2[t] = 2.0f * fmodf((float)t * PHI_F, TWO_PI_F);
  } else if (id < 1837568){
    int t = id - 1837056;
    bc[t] = ipbr[t] + ipbi[t];
  } else if (id < 1837576){
    int t = id - 1837568;
    alph[t] = 1.0f/(1.0f + expf(-la[t]));
  }
}

// ---------------- phase 1: h-recurrence, chunked restart ----------------
__global__ __launch_bounds__(256) void scan_h(const float* __restrict__ w,
                                              const float* __restrict__ bb,
                                              const float* __restrict__ tphi2,
                                              u32* __restrict__ X32){
  const int e = blockIdx.x*256 + threadIdx.x;   // 0..4095 = B*D
  const int c = blockIdx.y;                     // chunk
  const int b = e >> 9;
  const int d = e & 511;
  const float SQRT2 = 1.41421356237309504880f;
  const float PI_4  = 0.78539816339744830962f;
  const int tstart = c*CL;
  int t0 = tstart - CW; if (t0 < 0) t0 = 0;
  const int nw = tstart - t0;                   // 0,16,32 (multiple of 8)

  const float* wp = w  + ((size_t)b*SS + t0)*DD + d;
  const float* bp = bb + ((size_t)b*SS + t0)*DD + d;
  const float* tp = tphi2 + t0;

  const int U = 8;
  float wv[U], bv[U], wn[U], bn[U];

  float ss = 0.f;   // sin(theta + pi/4); hr+hi = sqrt2*ss
  const int ngw = nw >> 3;
  if (ngw > 0){
    #pragma unroll
    for (int i=0;i<U;i++){ wv[i] = wp[(size_t)i*DD]; bv[i] = bp[(size_t)i*DD]; }
    for (int gg=0; gg<ngw; ++gg){
      if (gg+1 < ngw){
        const float* wnp = wp + (size_t)(gg+1)*U*DD;
        const float* bnp = bp + (size_t)(gg+1)*U*DD;
        #pragma unroll
        for (int i=0;i<U;i++){ wn[i] = wnp[(size_t)i*DD]; bn[i] = bnp[(size_t)i*DD]; }
      }
      #pragma unroll
      for (int i=0;i<U;i++){
        float rwl2 = SQRT2 * __builtin_amdgcn_rcpf(1.0f + fabsf(wv[i]));
        float cw   = fmaf(2.0f, bv[i], tp[gg*U+i]) + PI_4;
        ss = __sinf(fmaf(ss, rwl2, cw));
      }
      #pragma unroll
      for (int i=0;i<U;i++){ wv[i]=wn[i]; bv[i]=bn[i]; }
    }
  }
  float hs = SQRT2 * ss;   // = hr + hi

  const float* wq = wp + (size_t)nw*DD;
  const float* bq = bp + (size_t)nw*DD;
  const float* tq = tp + nw;
  u32* xp = X32 + (size_t)(b*SS + tstart)*512 + d;

  #pragma unroll
  for (int i=0;i<U;i++){ wv[i] = wq[(size_t)i*DD]; bv[i] = bq[(size_t)i*DD]; }
  for (int gg=0; gg<CL/U; ++gg){
    if (gg+1 < CL/U){
      const float* wnp = wq + (size_t)(gg+1)*U*DD;
      const float* bnp = bq + (size_t)(gg+1)*U*DD;
      #pragma unroll
      for (int i=0;i<U;i++){ wn[i] = wnp[(size_t)i*DD]; bn[i] = bnp[(size_t)i*DD]; }
    }
    #pragma unroll
    for (int i=0;i<U;i++){
      float rwl = __builtin_amdgcn_rcpf(1.0f + fabsf(wv[i]));
      float cc  = fmaf(2.0f, bv[i], tq[gg*U+i]);
      float theta = fmaf(hs, rwl, cc);
      float sn = __sinf(theta);
      float cs = __cosf(theta);
      hs = cs + sn;
      xp[(size_t)(gg*U+i)*512] = (u32)f2bf(cs) | ((u32)f2bf(sn) << 16);
    }
    #pragma unroll
    for (int i=0;i<U;i++){ wv[i]=wn[i]; bv[i]=bn[i]; }
  }
}

// ---------------- bf16 MFMA GEMM: C[M x N] = A[M x K] @ W[N x K]^T ----------------
// Round-14: A via LDS (R8's 3-buffer rotation, 2 gload_lds/thread/step, 24KB),
// B DIRECT from L2 via fragment-major coalesced 1KB loads into double-buffered
// registers (prefetched 1 step ahead). Halves LDS-pipe traffic (the measured
// ~23% MfmaUtil binder). Mixed vmcnt stream, in-order retirement:
//   per step issue [A(t+2):2, B(t+1):4]; wait vmcnt(6) steady (A(t),B(t) landed;
//   A(t+2),B(t+1) in flight), tail vmcnt(4)/vmcnt(0).
// W layout: Wfrag[((nb2*nK+ks)*4+s)*512 + lane*8] (see prep_all).
// EPI: 1 = f32 split C0/C1 stride 512; 2 = bf16->C2 stride N;
//      3 = bf16->C2 stride N with f32 bias[col] added before rounding.
template<int TAG, int EPI>
__global__ __launch_bounds__(256) void gemm_bf16(const u16* __restrict__ A,
                                                 const u16* __restrict__ W,
                                                 float* __restrict__ C0,
                                                 float* __restrict__ C1,
                                                 u16* __restrict__ C2,
                                                 const float* __restrict__ bias,
                                                 int N, int K){
  __shared__ __align__(16) u16 As[3][128*32];   // 8KB per buffer
  const int tid  = threadIdx.x;
  const int nwgx = gridDim.x;
  const int nwg  = nwgx * gridDim.y;
  const int lin  = blockIdx.y * nwgx + blockIdx.x;
  const int qq   = nwg >> 3;
  const int logi = (lin & 7) * qq + (lin >> 3);
  const int m0   = (logi / nwgx) * 128;
  const int n0   = (logi % nwgx) * 128;

  const int wave = tid >> 6;
  const int lane = tid & 63;
  const int wr   = wave >> 1, wc = wave & 1;
  const int l15  = lane & 15;
  const int g    = lane >> 4;

  // A staging: 2 gload16/thread cover 128 rows; involution source swizzle.
  const int rI   = lane >> 2;
  const int kgs  = (lane & 3) ^ ((lane >> 3) & 3);
  const int row0 = wave*32 + rI;
  const int row1 = wave*32 + 16 + rI;
  const u16* Asrc0 = A + (size_t)(m0 + row0) * K + kgs*8;
  const u16* Asrc1 = A + (size_t)(m0 + row1) * K + kgs*8;
  const int ld0 = (wave*2+0)*512;
  const int ld1 = (wave*2+1)*512;

  // B fragment-major base for this wave's n-64-block
  const int nK = K >> 5;
  const u16* Bf = W + ((size_t)((n0 >> 6) + wc) * nK) * 2048 + lane*8;

  f32x4 acc[4][4];
  #pragma unroll
  for (int i=0;i<4;i++)
    #pragma unroll
    for (int j=0;j<4;j++) acc[i][j] = (f32x4){0.f,0.f,0.f,0.f};

  s16x8 b0[4], b1[4];

#define STAGE_A(buf, koff) do {                    \
    gload16(Asrc0 + (koff), &As[buf][ld0]);        \
    gload16(Asrc1 + (koff), &As[buf][ld1]);        \
  } while(0)

#define LOADB(dst, hh) do {                                         \
    _Pragma("unroll")                                               \
    for (int s=0;s<4;s++)                                           \
      dst[s] = *(const s16x8*)(Bf + ((size_t)(hh)*4 + s)*512);      \
  } while(0)

#define PHASE(hh, bcur, bnxt) do {                                       \
    if ((hh)+2 < nK){                                                    \
      int nb = (hh)+2; nb -= (nb/3)*3;                                   \
      STAGE_A(nb, ((hh)+2)*32);                                          \
    }                                                                    \
    if ((hh)+1 < nK) LOADB(bnxt, (hh)+1);                                \
    {                                                                    \
      int rem = nK - 1 - (hh);                                           \
      if      (rem >= 2) asm volatile("s_waitcnt vmcnt(6)" ::: "memory");\
      else if (rem == 1) asm volatile("s_waitcnt vmcnt(4)" ::: "memory");\
      else               asm volatile("s_waitcnt vmcnt(0)" ::: "memory");\
    }                                                                    \
    __builtin_amdgcn_s_barrier();        /* A(hh) visible to all waves */\
    {                                                                    \
      int cb = (hh); cb -= (cb/3)*3;                                     \
      const u16* Ah = &As[cb][0];                                        \
      s16x8 af[4];                                                       \
      _Pragma("unroll")                                                  \
      for (int s=0;s<4;s++){                                             \
        int rA = wr*64 + s*16 + l15;                                     \
        af[s] = *(const s16x8*)&Ah[rA*32 + ((g ^ ((rA>>1)&3))*8)];       \
      }                                                                  \
      __builtin_amdgcn_s_setprio(1);                                     \
      _Pragma("unroll")                                                  \
      for (int mi=0;mi<4;mi++)                                           \
        _Pragma("unroll")                                                \
        for (int ni=0;ni<4;ni++)                                         \
          acc[mi][ni] = __builtin_amdgcn_mfma_f32_16x16x32_bf16(af[mi], bcur[ni], acc[mi][ni], 0, 0, 0); \
      __builtin_amdgcn_s_setprio(0);                                     \
    }                                                                    \
    asm volatile("" ::: "memory");                                       \
    __builtin_amdgcn_s_barrier();        /* reads of As[hh%3] complete */\
  } while(0)

  // prologue: A(0), A(1) staged; B(0) loaded
  STAGE_A(0, 0);
  STAGE_A(1, 32);
  LOADB(b0, 0);

  for (int h = 0; h < nK; h += 2){
    PHASE(h,   b0, b1);
    PHASE(h+1, b1, b0);
  }

#undef STAGE_A
#undef LOADB
#undef PHASE

  #pragma unroll
  for (int mi=0;mi<4;mi++){
    #pragma unroll
    for (int j=0;j<4;j++){
      int r = m0 + wr*64 + mi*16 + g*4 + j;
      #pragma unroll
      for (int ni=0;ni<4;ni++){
        int col = n0 + wc*64 + ni*16 + l15;
        float v = acc[mi][ni][j];
        if (EPI == 1){
          if (col < 512) C0[(size_t)r*512 + col]       = v;
          else           C1[(size_t)r*512 + (col-512)] = v;
        } else if (EPI == 2){
          C2[(size_t)r*N + col] = f2bf(v);
        } else {
          C2[(size_t)r*N + col] = f2bf(v + bias[col]);
        }
      }
    }
  }
}

// ---------------- LayerNorm: xc = LN(y)*g + b  (bf16 in — bias pre-added in gemm1) ----------------
__global__ __launch_bounds__(256) void ln_kernel(const u16* __restrict__ y,
                                                 const float* __restrict__ g,
                                                 const float* __restrict__ bb,
                                                 u16* __restrict__ xc){
  const int row  = blockIdx.x*4 + (threadIdx.x >> 6);
  const int lane = threadIdx.x & 63;
  s16x8 v = *(const s16x8*)(y + (size_t)row*512 + lane*8);
  float f[8];
  #pragma unroll
  for (int i=0;i<8;i++) f[i] = bf2f((u16)v[i]);
  float s = 0.f, s2 = 0.f;
  #pragma unroll
  for (int i=0;i<8;i++){ s += f[i]; s2 = fmaf(f[i], f[i], s2); }
  #pragma unroll
  for (int off=32; off>0; off>>=1){ s += __shfl_xor(s, off); s2 += __shfl_xor(s2, off); }
  float mean = s * (1.0f/512.0f);
  float var  = s2 * (1.0f/512.0f) - mean*mean;
  float rstd = rsqrtf(var + 1e-5f);
  float4 g0 = ((const float4*)g)[lane*2],  g1 = ((const float4*)g)[lane*2+1];
  float4 b0 = ((const float4*)bb)[lane*2], b1 = ((const float4*)bb)[lane*2+1];
  s16x8 o;
  o[0] = (short)f2bf((f[0]-mean)*rstd*g0.x + b0.x);
  o[1] = (short)f2bf((f[1]-mean)*rstd*g0.y + b0.y);
  o[2] = (short)f2bf((f[2]-mean)*rstd*g0.z + b0.z);
  o[3] = (short)f2bf((f[3]-mean)*rstd*g0.w + b0.w);
  o[4] = (short)f2bf((f[4]-mean)*rstd*g1.x + b1.x);
  o[5] = (short)f2bf((f[5]-mean)*rstd*g1.y + b1.y);
  o[6] = (short)f2bf((f[6]-mean)*rstd*g1.z + b1.z);
  o[7] = (short)f2bf((f[7]-mean)*rstd*g1.w + b1.w);
  *(s16x8*)(xc + (size_t)row*512 + lane*8) = o;
}

// ---------------- fused EMA + gate + retr ----------------
__global__ __launch_bounds__(256) void retr_fused(const u16* __restrict__ qkv,
                                                  const float* __restrict__ alph,
                                                  u16* __restrict__ retr){
  const int wid  = blockIdx.x*4 + (threadIdx.x >> 6);   // 0..2047
  const int lane = threadIdx.x & 63;
  const int c = wid & 31;                               // 32 chunks of RT=64
  const int h = (wid >> 5) & 7;
  const int b = wid >> 8;
  const float a  = alph[h];
  const float om = 1.0f - a;
  const int d  = h*64 + lane;
  const int t0 = c*RT;
  int w0 = t0 - RW; if (w0 < 0) w0 = 0;
  const int nw = t0 - w0;                      // multiple of 32

  const u16* vp = qkv + ((size_t)(b*SS + w0))*1536 + 1024 + d;
  float vs = 0.f;
  {
    const int U = 8;
    float vv[U], vn[U];
    const int ng = nw >> 3;
    if (ng > 0){
      #pragma unroll
      for (int i=0;i<U;i++) vv[i] = bf2f(vp[(size_t)i*1536]);
      for (int gg=0; gg<ng; ++gg){
        if (gg+1 < ng){
          const u16* vnp = vp + (size_t)(gg+1)*U*1536;
          #pragma unroll
          for (int i=0;i<U;i++) vn[i] = bf2f(vnp[(size_t)i*1536]);
        }
        #pragma unroll
        for (int i=0;i<U;i++) vs = fmaf(a, vv[i], om*vs);
        #pragma unroll
        for (int i=0;i<U;i++) vv[i] = vn[i];
      }
    }
  }
  const u16* qp = qkv + ((size_t)(b*SS + t0))*1536 + d;
  u16* op = retr + ((size_t)(b*SS + t0))*512 + d;
  #pragma unroll 4
  for (int i=0;i<RT;i++){
    float q  = bf2f(qp[(size_t)i*1536]);
    float kk = bf2f(qp[(size_t)i*1536 + 512]);
    float v  = bf2f(qp[(size_t)i*1536 + 1024]);
    vs = fmaf(a, v, om*vs);
    float p = q*kk;
    #pragma unroll
    for (int off=32; off>0; off>>=1) p += __shfl_xor(p, off);
    float gate = 1.0f/(1.0f + __expf(-p*0.125f));
    op[(size_t)i*512] = f2bf(gate * vs);
  }
}

extern "C" void kernel_launch(void* const* d_in, const int* in_sizes, int n_in,
                              void* d_out, int out_size, void* d_ws, size_t ws_size,
                              hipStream_t stream) {
  const float* w    = (const float*)d_in[0];
  const float* b    = (const float*)d_in[1];
  const float* ipWr = (const float*)d_in[2];
  const float* ipWi = (const float*)d_in[3];
  const float* ipbr = (const float*)d_in[4];
  const float* ipbi = (const float*)d_in[5];
  const float* lng  = (const float*)d_in[6];
  const float* lnb  = (const float*)d_in[7];
  const float* Wqkv = (const float*)d_in[8];
  const float* la   = (const float*)d_in[9];
  const float* opWr = (const float*)d_in[10];
  const float* opWi = (const float*)d_in[11];
  float* out0 = (float*)d_out;                    // (B,S,D) real part
  float* out1 = out0 + (size_t)MM*DD;             // imag part

  char* base = (char*)d_ws;
  u16*   W1    = (u16*)  (base + 0);              // 512x1024 bf16 fragment-major
  u16*   Wq    = (u16*)  (base + 1048576);        // 1536x512 bf16 fragment-major
  u16*   W3    = (u16*)  (base + 2621440);        // 1024x512 bf16 fragment-major
  float* bc    = (float*)(base + 3670016);        // 512 f32
  float* alph  = (float*)(base + 3672064);        // 8 f32
  float* tphi2 = (float*)(base + 3672128);        // 2048 f32
  u32*   X32   = (u32*)  (base + 3680384);        // M*512 u32 (packed bf16 pair)
  u16*   y     = (u16*)  (base + 37234816);       // M*512 bf16
  u16*   xc    = (u16*)  (base + 54012032);       // M*512 bf16
  u16*   qkv   = (u16*)  (base + 70789248);       // M*1536 bf16
  u16*   retr  = (u16*)X32;                       // alias: X dead after GEMM1

  prep_all<<<7179,256,0,stream>>>(ipWr, ipWi, Wqkv, opWr, opWi, ipbr, ipbi, la,
                                  W1, Wq, W3, tphi2, bc, alph);

  scan_h<<<dim3(16,CHK),256,0,stream>>>(w, b, tphi2, X32);

  gemm_bf16<1,3><<<dim3(4,128),256,0,stream>>>((const u16*)X32, W1, nullptr, nullptr, y, bc, 512, 1024);
  ln_kernel<<<4096,256,0,stream>>>(y, lng, lnb, xc);
  gemm_bf16<2,2><<<dim3(12,128),256,0,stream>>>(xc, Wq, nullptr, nullptr, qkv, nullptr, 1536, 512);

  retr_fused<<<512,256,0,stream>>>(qkv, alph, retr);

  gemm_bf16<3,1><<<dim3(8,128),256,0,stream>>>(retr, W3, out0, out1, nullptr, nullptr, 1024, 512);
}